// Round 5
// baseline (506.689 us; speedup 1.0000x reference)
//
#include <hip/hip_runtime.h>
#include <hip/hip_bf16.h>
#include <stdint.h>

// MoE: N=8192 tokens, H=1024, E=16 experts (top-2), I=512, shared IS=2048.
// R9: (1) B-fragments held in registers across the K-tile: 32->24
//     ds_read_b128/wave/kt; ph3 pure-MFMA, 7 barriers/kt (ledger safe).
//     (2) XCD-bijective swizzle within each 512-block half of the merged
//     sg1+eg1 grid (8x64 transpose) for L2 A-panel locality.
//     (3) sg2c: both-sides XOR swizzle (blk ^= row&3) kills the 8-way
//     bank conflict on fragment reads (-> 4-way).

#define N_TOK 8192
#define HDIM 1024
#define NEXP 16
#define IEXP 512
#define ISH 2048

typedef __bf16 bf16x8 __attribute__((ext_vector_type(8)));
typedef float f32x4 __attribute__((ext_vector_type(4)));

// ---- ws layout (bytes) ----
#define OFF_XBF   ((size_t)0)            // 16,777,216
#define OFF_WSG   ((size_t)16777216)     // 4,194,304
#define OFF_WSU   ((size_t)20971520)
#define OFF_WSD   ((size_t)25165824)
#define OFF_SH    ((size_t)29360128)     // 33,554,432 (sh; live until sg2c)
#define OFF_HEXP  ((size_t)62914560)     // 16,777,216
#define OFF_IDS   ((size_t)79691776)     // 16*8192*4 = 524,288
#define OFF_META  ((size_t)80216064)     // 256 B: cnt[16]@0, off[17]@64, pps[16]@144
#define OFF_SIG   ((size_t)80216320)     // 8192*4
#define OFF_LG    ((size_t)80249088)     // 8192*32*4 = 1,048,576
#define OFF_SLOT  ((size_t)81297664)     // 2*8192*4
#define OFF_TWAB  ((size_t)81363200)     // 2*8192*4  (end = 81,428,736)

#define WGU_NEW   ((size_t)81428736)                 // 33,554,432 (wgu -> eout)
#define WDN_NEW   ((size_t)(WGU_NEW + 33554432))     // 16,777,216
#define NEED_FULL ((size_t)(WDN_NEW + 16777216))     // 131,760,384

static __device__ __forceinline__ unsigned short f2bf(float f) {
  unsigned int u = __float_as_uint(f);
  u += 0x7fffu + ((u >> 16) & 1u);
  return (unsigned short)(u >> 16);
}
static __device__ __forceinline__ int pack_bf2(float a, float b) {
  return (int)f2bf(a) | ((int)f2bf(b) << 16);
}
static __device__ __forceinline__ float bf2f(unsigned short u) {
  return __uint_as_float(((unsigned int)u) << 16);
}
// async 16B global->LDS (LDS dest is wave-uniform base + lane*16)
static __device__ __forceinline__ void gl_lds16(const void* g, void* l) {
  __builtin_amdgcn_global_load_lds(
      (const __attribute__((address_space(1))) unsigned int*)g,
      (__attribute__((address_space(3))) unsigned int*)l, 16, 0, 0);
}

__global__ void cvt_kernel(const float* __restrict__ src,
                           unsigned short* __restrict__ dst, int n4) {
  int i = blockIdx.x * 256 + threadIdx.x;
  if (i >= n4) return;
  float4 v = ((const float4*)src)[i];
  uint2 o;
  o.x = (unsigned)pack_bf2(v.x, v.y);
  o.y = (unsigned)pack_bf2(v.z, v.w);
  ((uint2*)dst)[i] = o;
}

// all 5 weight converts in one dispatch (full path)
#define CV_WSG 524288
#define CV_WSU 1048576
#define CV_WSD 1572864
#define CV_WGU 5767168
#define CV_ALL 7864320
__global__ void cvt5_kernel(const float* __restrict__ WSG, const float* __restrict__ WSU,
                            const float* __restrict__ WSD, const float* __restrict__ WGU,
                            const float* __restrict__ WDN,
                            unsigned short* __restrict__ wsg, unsigned short* __restrict__ wsu,
                            unsigned short* __restrict__ wsd, unsigned short* __restrict__ wgu,
                            unsigned short* __restrict__ wdn) {
  int i = blockIdx.x * 256 + threadIdx.x;
  if (i >= CV_ALL) return;
  const float* src; unsigned short* dst; int k;
  if (i < CV_WSG)      { src = WSG; dst = wsg; k = i; }
  else if (i < CV_WSU) { src = WSU; dst = wsu; k = i - CV_WSG; }
  else if (i < CV_WSD) { src = WSD; dst = wsd; k = i - CV_WSU; }
  else if (i < CV_WGU) { src = WGU; dst = wgu; k = i - CV_WSD; }
  else                 { src = WDN; dst = wdn; k = i - CV_WGU; }
  float4 v = ((const float4*)src)[k];
  uint2 o;
  o.x = (unsigned)pack_bf2(v.x, v.y);
  o.y = (unsigned)pack_bf2(v.z, v.w);
  ((uint2*)dst)[k] = o;
}

// ---- phase 1: logits (wave/token) + fused X->bf16 convert
__global__ __launch_bounds__(256) void logits_kernel(
    const float* __restrict__ X, const float* __restrict__ GW,
    const float* __restrict__ SEGW, float* __restrict__ LG,
    unsigned short* __restrict__ XBF) {
  int wid = threadIdx.x >> 6, lane = threadIdx.x & 63;
  int tok = blockIdx.x * 4 + wid;
  const float* xr = X + (size_t)tok * HDIM;
  unsigned short* xw = XBF + (size_t)tok * HDIM;
  float xv[16];
#pragma unroll
  for (int i = 0; i < 16; i++) xv[i] = xr[lane + 64 * i];
#pragma unroll
  for (int i = 0; i < 16; i++) xw[lane + 64 * i] = f2bf(xv[i]);
  float myv = 0.f;
#pragma unroll
  for (int e = 0; e < 17; e++) {
    const float* wr = (e < 16) ? (GW + (size_t)e * HDIM) : SEGW;
    float p = 0.f;
#pragma unroll
    for (int i = 0; i < 16; i++) p += xv[i] * wr[lane + 64 * i];
#pragma unroll
    for (int off = 32; off >= 1; off >>= 1) p += __shfl_xor(p, off, 64);
    if (lane == e) myv = p;
  }
  if (lane < 17) LG[(size_t)tok * 32 + lane] = myv;
}

// ---- phase 2: softmax/top2/scatter
__global__ __launch_bounds__(256) void route_kernel(
    const float* __restrict__ LG, int* __restrict__ cnt,
    float* __restrict__ pps, int* __restrict__ ids,
    int* __restrict__ slotAB, float* __restrict__ twAB,
    float* __restrict__ sig) {
  __shared__ int lcnt[16];
  __shared__ int lbase[16];
  __shared__ float lps[16];
  int tid = threadIdx.x;
  int tok = blockIdx.x * 256 + tid;
  if (tid < 16) { lcnt[tid] = 0; lps[tid] = 0.f; }
  __syncthreads();
  const float4* row = (const float4*)(LG + (size_t)tok * 32);
  float4 v0 = row[0], v1 = row[1], v2 = row[2], v3 = row[3];
  float g16 = row[4].x;
  float lg[16] = {v0.x, v0.y, v0.z, v0.w, v1.x, v1.y, v1.z, v1.w,
                  v2.x, v2.y, v2.z, v2.w, v3.x, v3.y, v3.z, v3.w};
  float mx = lg[0];
#pragma unroll
  for (int e = 1; e < 16; e++) mx = fmaxf(mx, lg[e]);
  float pr[16], s = 0.f;
#pragma unroll
  for (int e = 0; e < 16; e++) { pr[e] = __expf(lg[e] - mx); s += pr[e]; }
  float inv_s = 1.f / s;
  float p1 = -1.f, p2 = -1.f; int i1 = 0, i2 = 0;
#pragma unroll
  for (int e = 0; e < 16; e++) {
    if (pr[e] > p1) { p2 = p1; i2 = i1; p1 = pr[e]; i1 = e; }
    else if (pr[e] > p2) { p2 = pr[e]; i2 = e; }
  }
  float wsum = p1 + p2;
  int s1 = atomicAdd(&lcnt[i1], 1);
  int s2 = atomicAdd(&lcnt[i2], 1);
#pragma unroll
  for (int e = 0; e < 16; e++) atomicAdd(&lps[e], pr[e] * inv_s);
  sig[tok] = 1.f / (1.f + __expf(-g16));
  __syncthreads();
  if (tid < 16) {
    lbase[tid] = atomicAdd(&cnt[tid], lcnt[tid]);
    atomicAdd(&pps[tid], lps[tid]);
  }
  __syncthreads();
  int sl1 = lbase[i1] + s1, sl2 = lbase[i2] + s2;
  ids[i1 * N_TOK + sl1] = tok;
  ids[i2 * N_TOK + sl2] = tok;
  slotAB[tok * 2]     = (i1 << 14) | sl1;
  slotAB[tok * 2 + 1] = (i2 << 14) | sl2;
  twAB[tok * 2]     = p1 / wsum;
  twAB[tok * 2 + 1] = p2 / wsum;
}

__global__ void offs_aux_kernel(const int* __restrict__ cnt, int* __restrict__ off,
                                const float* __restrict__ probs_sum,
                                float* __restrict__ out_aux) {
  if (threadIdx.x == 0 && blockIdx.x == 0) {
    int run = 0; float aux = 0.f;
    for (int e = 0; e < NEXP; e++) {
      off[e] = run; run += cnt[e];
      aux += ((float)cnt[e] / (float)(N_TOK * 2)) * (probs_sum[e] / (float)N_TOK);
    }
    off[16] = run;
    *out_aux = (float)NEXP * aux;
  }
}

// ======================================================================
// 256x256 BK=64 8-phase GEMM core, strict schedule, B-in-regs (R9):
// per kt: ph0 {rd A-lo(8)+B-lo(4); STG nb.Ahi; BAR; lgkm0; 16 MFMA; BAR}
//         ph1 {rd B-hi(4); STG nb.Blo; BAR; lgkm0; 16 MFMA; BAR}
//         ph2 {rd A-hi(8); STG c.Alo(kt+2); BAR; lgkm0; 16 MFMA; BAR}
//         ph3 {STG c.Bhi(kt+2); 16 MFMA (regs only); vmcnt(4); BAR}
// 24 ds_read_b128/wave/kt (was 32), 7 barriers/kt (was 8).
// WAR ledger: every STG target's last LDS-read completed >=2 barriers
// before the STG issue point (B-lo now read only in ph0 -> safer).
// Swizzle: source 16B-block cb = blk^(row&7), LDS linear, ds_read same
// involution -> 0 bank conflicts.
// TMODE 0: sg1  A=xbf dense,    B=wsg/wsu 16-row interleave, silu -> sh
// TMODE 1: eg1  A=xbf gathered, B=wgu     16-row interleave, silu -> hexp
// TMODE 2: eg2  A=hexp,         B=wdn,    raw bf16 -> Eout
// TMODE 3: merged sg1+eg1, XCD-swizzled within each 512-block half
// ======================================================================
template <int TMODE>
__global__ __launch_bounds__(512, 2) void g8p_kernel(
    const unsigned short* __restrict__ A0,
    const unsigned short* __restrict__ Bg,
    const unsigned short* __restrict__ Bu,
    const unsigned short* __restrict__ Bgu,
    const unsigned short* __restrict__ Bd,
    const int* __restrict__ ids, const int* __restrict__ cnt,
    const int* __restrict__ off,
    unsigned short* __restrict__ Osh,
    unsigned short* __restrict__ Ohex,
    unsigned short* __restrict__ Oeout) {
  constexpr int KD = (TMODE == 2) ? IEXP : HDIM;
  constexpr int NK = KD / 64;
  extern __shared__ unsigned short lds[];

  int rmode, e = 0, bx, by, m0step;
  if constexpr (TMODE == 3) {
    int id0 = blockIdx.x;
    // XCD-bijective transpose within each 512-block half: XCD k gets a
    // contiguous 64-tile chunk of each half (balanced sg1/eg1 load).
    int id;
    if (id0 < 512) id = (id0 & 7) * 64 + (id0 >> 3);
    else { int q = id0 - 512; id = 512 + (q & 7) * 64 + (q >> 3); }
    if (id < 512) { rmode = 0; bx = id & 15; by = id >> 4; m0step = 8192; }
    else {
      int id2 = id - 512;
      rmode = 1; e = id2 >> 5; bx = id2 & 3; by = (id2 >> 2) & 7; m0step = 2048;
    }
  } else if constexpr (TMODE == 0) {
    rmode = 0; bx = blockIdx.x; by = blockIdx.y; m0step = 8192;
  } else if constexpr (TMODE == 1) {
    rmode = 1; e = blockIdx.z; bx = blockIdx.x; by = blockIdx.y;
    m0step = (int)gridDim.y * 256;
  } else {
    rmode = 2; e = blockIdx.z; bx = blockIdx.x; by = blockIdx.y;
    m0step = (int)gridDim.y * 256;
  }

  int ne, base = 0;
  if (rmode == 0) { ne = N_TOK; }
  else { ne = cnt[e]; base = off[e]; }

  const int t = threadIdx.x, lane = t & 63, w = t >> 6;
  const int fr = lane & 15, hi = lane >> 4;
  const int rq = hi * 4;
  const int Rm = (w >> 2) * 64;   // wave M base within a 128-row half
  const int wn = (w & 3) * 32;    // wave B-row base within a 128-row half
  const int srow = t >> 3;        // staging row-in-load
  const int sblk = t & 7;
  const int cb = (sblk ^ (srow & 7)) * 8;  // swizzled source k-elem offset
  const int s0 = ((0 + hi) ^ (fr & 7)) * 8;
  const int s1 = ((4 + hi) ^ (fr & 7)) * 8;
  const f32x4 z4 = {0.f, 0.f, 0.f, 0.f};

#define STG_A(buf, h, kt)                                                     \
  do {                                                                        \
    gl_lds16(apt[h][0] + (kt) * 64, &lds[(buf)*32768 + (h)*8192 + t * 8]);    \
    gl_lds16(apt[h][1] + (kt) * 64,                                           \
             &lds[(buf)*32768 + (h)*8192 + 4096 + t * 8]);                    \
  } while (0)
#define STG_B(buf, h, kt)                                                     \
  do {                                                                        \
    gl_lds16(bpt[h][0] + (kt) * 64,                                           \
             &lds[(buf)*32768 + 16384 + (h)*8192 + t * 8]);                   \
    gl_lds16(bpt[h][1] + (kt) * 64,                                           \
             &lds[(buf)*32768 + 16384 + (h)*8192 + 4096 + t * 8]);            \
  } while (0)

  for (int m0 = by * 256; m0 < ne; m0 += m0step) {
    // ---- per-thread staging source pointers (row fixed across K) ----
    const unsigned short* apt[2][2];
    const unsigned short* bpt[2][2];
#pragma unroll
    for (int h = 0; h < 2; h++)
#pragma unroll
      for (int l = 0; l < 2; l++) {
        int r = h * 128 + l * 64 + srow;
        // A row
        if (rmode == 0) {
          apt[h][l] = A0 + (size_t)(m0 + r) * HDIM + cb;
        } else if (rmode == 1) {
          int slot = m0 + r;
          int arow = (slot < ne) ? ids[e * N_TOK + slot] : 0;
          apt[h][l] = A0 + (size_t)arow * HDIM + cb;
        } else {
          int ra = base + m0 + r;
          if (ra > 16383) ra = 16383;
          apt[h][l] = A0 + (size_t)ra * IEXP + cb;
        }
        // B row
        if (rmode == 0) {
          int gcol = bx * 128 + ((r >> 5) << 4) + (r & 15);
          const unsigned short* W = (r & 16) ? Bu : Bg;
          bpt[h][l] = W + (size_t)gcol * HDIM + cb;
        } else if (rmode == 1) {
          int wrow = ((r & 16) ? 512 : 0) + bx * 128 + ((r >> 5) << 4) + (r & 15);
          bpt[h][l] = Bgu + ((size_t)e * 1024 + wrow) * HDIM + cb;
        } else {
          int nrow = bx * 256 + r;
          bpt[h][l] = Bd + ((size_t)e * HDIM + nrow) * IEXP + cb;
        }
      }

    f32x4 acc[8][4];
#pragma unroll
    for (int i = 0; i < 8; i++)
#pragma unroll
      for (int j = 0; j < 4; j++) acc[i][j] = z4;

    // ---- prologue: tile0 all 4 halves + tile1 {A-lo, B-hi} ----
    STG_A(0, 0, 0); STG_B(0, 1, 0); STG_A(0, 1, 0); STG_B(0, 0, 0);
    STG_A(1, 0, 1); STG_B(1, 1, 1);
    asm volatile("s_waitcnt vmcnt(4)" ::: "memory");
    __builtin_amdgcn_s_barrier();

    for (int kt = 0; kt < NK; ++kt) {
      const int c = kt & 1, nb = c ^ 1;
      const unsigned short* Ab = &lds[c * 32768];
      const unsigned short* Bb = &lds[c * 32768 + 16384];
      bf16x8 a[4][2], bl[2][2], bh[2][2];

      // ---- phase 0: read A-lo + B-lo; MFMA (A-lo x B-lo) ----
#pragma unroll
      for (int i = 0; i < 4; i++) {
        int ro = (Rm + i * 16 + fr) * 64;
        a[i][0] = *(const bf16x8*)&Ab[ro + s0];
        a[i][1] = *(const bf16x8*)&Ab[ro + s1];
      }
#pragma unroll
      for (int j = 0; j < 2; j++) {
        int ro = (wn + j * 16 + fr) * 64;
        bl[j][0] = *(const bf16x8*)&Bb[ro + s0];
        bl[j][1] = *(const bf16x8*)&Bb[ro + s1];
      }
      if (kt + 1 < NK) STG_A(nb, 1, kt + 1);
      __builtin_amdgcn_s_barrier();
      asm volatile("s_waitcnt lgkmcnt(0)" ::: "memory");
      __builtin_amdgcn_s_setprio(1);
#pragma unroll
      for (int i = 0; i < 4; i++)
#pragma unroll
        for (int j = 0; j < 2; j++) {
          acc[i][j] = __builtin_amdgcn_mfma_f32_16x16x32_bf16(a[i][0], bl[j][0], acc[i][j], 0, 0, 0);
          acc[i][j] = __builtin_amdgcn_mfma_f32_16x16x32_bf16(a[i][1], bl[j][1], acc[i][j], 0, 0, 0);
        }
      __builtin_amdgcn_s_setprio(0);
      __builtin_amdgcn_s_barrier();

      // ---- phase 1: read B-hi; MFMA (A-lo x B-hi) ----
#pragma unroll
      for (int j = 0; j < 2; j++) {
        int ro = (128 + wn + j * 16 + fr) * 64;
        bh[j][0] = *(const bf16x8*)&Bb[ro + s0];
        bh[j][1] = *(const bf16x8*)&Bb[ro + s1];
      }
      if (kt + 1 < NK) STG_B(nb, 0, kt + 1);
      __builtin_amdgcn_s_barrier();
      asm volatile("s_waitcnt lgkmcnt(0)" ::: "memory");
      __builtin_amdgcn_s_setprio(1);
#pragma unroll
      for (int i = 0; i < 4; i++)
#pragma unroll
        for (int j = 0; j < 2; j++) {
          acc[i][2 + j] = __builtin_amdgcn_mfma_f32_16x16x32_bf16(a[i][0], bh[j][0], acc[i][2 + j], 0, 0, 0);
          acc[i][2 + j] = __builtin_amdgcn_mfma_f32_16x16x32_bf16(a[i][1], bh[j][1], acc[i][2 + j], 0, 0, 0);
        }
      __builtin_amdgcn_s_setprio(0);
      __builtin_amdgcn_s_barrier();

      // ---- phase 2: read A-hi (overwrite a); MFMA (A-hi x B-hi) ----
#pragma unroll
      for (int i = 0; i < 4; i++) {
        int ro = (128 + Rm + i * 16 + fr) * 64;
        a[i][0] = *(const bf16x8*)&Ab[ro + s0];
        a[i][1] = *(const bf16x8*)&Ab[ro + s1];
      }
      if (kt + 2 < NK) STG_A(c, 0, kt + 2);
      __builtin_amdgcn_s_barrier();
      asm volatile("s_waitcnt lgkmcnt(0)" ::: "memory");
      __builtin_amdgcn_s_setprio(1);
#pragma unroll
      for (int i = 0; i < 4; i++)
#pragma unroll
        for (int j = 0; j < 2; j++) {
          acc[4 + i][2 + j] = __builtin_amdgcn_mfma_f32_16x16x32_bf16(a[i][0], bh[j][0], acc[4 + i][2 + j], 0, 0, 0);
          acc[4 + i][2 + j] = __builtin_amdgcn_mfma_f32_16x16x32_bf16(a[i][1], bh[j][1], acc[4 + i][2 + j], 0, 0, 0);
        }
      __builtin_amdgcn_s_setprio(0);
      __builtin_amdgcn_s_barrier();

      // ---- phase 3: pure MFMA (A-hi x B-lo from regs); no pre-barrier ----
      if (kt + 2 < NK) STG_B(c, 1, kt + 2);
      __builtin_amdgcn_s_setprio(1);
#pragma unroll
      for (int i = 0; i < 4; i++)
#pragma unroll
        for (int j = 0; j < 2; j++) {
          acc[4 + i][j] = __builtin_amdgcn_mfma_f32_16x16x32_bf16(a[i][0], bl[j][0], acc[4 + i][j], 0, 0, 0);
          acc[4 + i][j] = __builtin_amdgcn_mfma_f32_16x16x32_bf16(a[i][1], bl[j][1], acc[4 + i][j], 0, 0, 0);
        }
      __builtin_amdgcn_s_setprio(0);
      if (kt + 2 < NK) asm volatile("s_waitcnt vmcnt(4)" ::: "memory");
      else             asm volatile("s_waitcnt vmcnt(0)" ::: "memory");
      __builtin_amdgcn_s_barrier();
    }

    // ---- epilogue ----
#pragma unroll
    for (int i = 0; i < 8; i++) {
      int mloc = (i >> 2) * 128 + Rm + (i & 3) * 16 + rq;
      if (rmode == 2) {
#pragma unroll
        for (int j = 0; j < 4; j++) {
          int nn = bx * 256 + (j >> 1) * 128 + wn + (j & 1) * 16 + fr;
#pragma unroll
          for (int r = 0; r < 4; r++) {
            int slot = m0 + mloc + r;
            if (slot < ne)
              Oeout[(size_t)(base + slot) * HDIM + nn] = f2bf(acc[i][j][r]);
          }
        }
      } else {
        // silu(g)*u, bf16 store
#pragma unroll
        for (int p = 0; p < 2; p++) {
          int cc = bx * 128 + p * 64 + (w & 3) * 16 + fr;
#pragma unroll
          for (int r = 0; r < 4; r++) {
            int slot = m0 + mloc + r;
            float g = acc[i][2 * p][r], u = acc[i][2 * p + 1][r];
            float hv = g / (1.f + __expf(-g)) * u;
            if (rmode == 0) {
              Osh[(size_t)slot * ISH + cc] = f2bf(hv);
            } else if (slot < ne) {
              Ohex[(size_t)(base + slot) * IEXP + cc] = f2bf(hv);
            }
          }
        }
      }
    }
  }
#undef STG_A
#undef STG_B
}

// ---- sg2 (+ optional fused combine): Out = (H@Wd^T)*sig [+ twA*eoutA + twB*eoutB]
// 128x128 tile, 256 threads. R9: both-sides XOR swizzle (blk ^= row&3) on
// the 4x16B row blocks: fragment-read conflict 8-way -> 4-way.
template <int FUSE>
__global__ __launch_bounds__(256) void sg2c_kernel(
    const unsigned short* __restrict__ H, const unsigned short* __restrict__ Wd,
    const float* __restrict__ sig, const unsigned short* __restrict__ Eout,
    const int* __restrict__ slotAB, const float* __restrict__ twAB,
    const int* __restrict__ off, float* __restrict__ Out) {
  __shared__ __align__(16) unsigned short As[128 * 32];
  __shared__ __align__(16) unsigned short Bs[128 * 32];
  int m0 = blockIdx.y * 128, n0 = blockIdx.x * 128;
  int t = threadIdx.x, lane = t & 63, w = t >> 6;
  int wm = (w & 1) * 64, wn = (w >> 1) * 64;
  int arow = t >> 2;
  int akb = ((t & 3) ^ (arow & 3)) * 8;  // swizzled source column-block
  const unsigned short* apA0 = H + (size_t)(m0 + arow) * ISH + akb;
  const unsigned short* apA1 = H + (size_t)(m0 + 64 + arow) * ISH + akb;
  const unsigned short* apB0 = Wd + (size_t)(n0 + arow) * ISH + akb;
  const unsigned short* apB1 = Wd + (size_t)(n0 + 64 + arow) * ISH + akb;
  f32x4 z = {0.f, 0.f, 0.f, 0.f};
  f32x4 acc[4][4];
#pragma unroll
  for (int i = 0; i < 4; i++)
#pragma unroll
    for (int j = 0; j < 4; j++) acc[i][j] = z;
  int fr = lane & 15;
  int fcs = (((lane >> 4) ^ (fr & 3))) * 8;  // swizzled read block (row&3 == fr&3)
  for (int k0 = 0; k0 < ISH; k0 += 32) {
    __syncthreads();
    gl_lds16(apA0 + k0, &As[t * 8]);
    gl_lds16(apA1 + k0, &As[2048 + t * 8]);
    gl_lds16(apB0 + k0, &Bs[t * 8]);
    gl_lds16(apB1 + k0, &Bs[2048 + t * 8]);
    __syncthreads();
    bf16x8 af[4], bfr[4];
#pragma unroll
    for (int i = 0; i < 4; i++) {
      af[i] = *(const bf16x8*)&As[(wm + i * 16 + fr) * 32 + fcs];
      bfr[i] = *(const bf16x8*)&Bs[(wn + i * 16 + fr) * 32 + fcs];
    }
#pragma unroll
    for (int i = 0; i < 4; i++)
#pragma unroll
      for (int j = 0; j < 4; j++)
        acc[i][j] = __builtin_amdgcn_mfma_f32_16x16x32_bf16(af[i], bfr[j], acc[i][j], 0, 0, 0);
  }
  int col = lane & 15, rq = (lane >> 4) * 4;
#pragma unroll
  for (int i = 0; i < 4; i++)
#pragma unroll
    for (int r = 0; r < 4; r++) {
      int mm = m0 + wm + i * 16 + rq + r;
      float sg = sig[mm];
      if (FUSE) {
        int sa = slotAB[mm * 2], sb = slotAB[mm * 2 + 1];
        float wa = twAB[mm * 2], wb = twAB[mm * 2 + 1];
        size_t ra = (size_t)(off[sa >> 14] + (sa & 16383)) * HDIM;
        size_t rb = (size_t)(off[sb >> 14] + (sb & 16383)) * HDIM;
#pragma unroll
        for (int j = 0; j < 4; j++) {
          int nn = n0 + wn + j * 16 + col;
          float ea = bf2f(Eout[ra + nn]);
          float eb = bf2f(Eout[rb + nn]);
          Out[(size_t)mm * HDIM + nn] = acc[i][j][r] * sg + wa * ea + wb * eb;
        }
      } else {
#pragma unroll
        for (int j = 0; j < 4; j++) {
          int nn = n0 + wn + j * 16 + col;
          Out[(size_t)mm * HDIM + nn] = acc[i][j][r] * sg;
        }
      }
    }
}

// ---- combine (fallback path only): Out[tok] += twA*eout[rowA] + twB*eout[rowB]
__global__ __launch_bounds__(256) void combine_kernel(
    const unsigned short* __restrict__ Eout, const int* __restrict__ slotAB,
    const float* __restrict__ twAB, const int* __restrict__ off,
    float* __restrict__ Out) {
  int tok = blockIdx.x, t = threadIdx.x;
  int sa = slotAB[tok * 2], sb = slotAB[tok * 2 + 1];
  float wa = twAB[tok * 2], wb = twAB[tok * 2 + 1];
  int ra = off[sa >> 14] + (sa & 16383);
  int rb = off[sb >> 14] + (sb & 16383);
  const ushort4 a4 = *(const ushort4*)(Eout + (size_t)ra * HDIM + t * 4);
  const ushort4 b4 = *(const ushort4*)(Eout + (size_t)rb * HDIM + t * 4);
  float* po = Out + (size_t)tok * HDIM + t * 4;
  float4 o = *(const float4*)po;
  o.x += wa * bf2f(a4.x) + wb * bf2f(b4.x);
  o.y += wa * bf2f(a4.y) + wb * bf2f(b4.y);
  o.z += wa * bf2f(a4.z) + wb * bf2f(b4.z);
  o.w += wa * bf2f(a4.w) + wb * bf2f(b4.w);
  *(float4*)po = o;
}

extern "C" void kernel_launch(void* const* d_in, const int* in_sizes, int n_in,
                              void* d_out, int out_size, void* d_ws, size_t ws_size,
                              hipStream_t stream) {
  const float* X   = (const float*)d_in[0];
  const float* GW  = (const float*)d_in[1];
  const float* WGU = (const float*)d_in[2];
  const float* WDN = (const float*)d_in[3];
  const float* WSG = (const float*)d_in[4];
  const float* WSU = (const float*)d_in[5];
  const float* WSD = (const float*)d_in[6];
  const float* SEGW = (const float*)d_in[7];
  float* Out = (float*)d_out;
  char* ws = (char*)d_ws;

  unsigned short* xbf  = (unsigned short*)(ws + OFF_XBF);
  unsigned short* wsg  = (unsigned short*)(ws + OFF_WSG);
  unsigned short* wsu  = (unsigned short*)(ws + OFF_WSU);
  unsigned short* wsd  = (unsigned short*)(ws + OFF_WSD);
  unsigned short* sh   = (unsigned short*)(ws + OFF_SH);
  unsigned short* hexp = (unsigned short*)(ws + OFF_HEXP);
  int*   ids  = (int*)(ws + OFF_IDS);
  int*   cnt  = (int*)(ws + OFF_META);
  int*   off  = (int*)(ws + OFF_META + 64);
  float* pps  = (float*)(ws + OFF_META + 144);
  float* sig  = (float*)(ws + OFF_SIG);
  float* lg   = (float*)(ws + OFF_LG);
  int*   slotAB = (int*)(ws + OFF_SLOT);
  float* twAB   = (float*)(ws + OFF_TWAB);

  const bool full = (ws_size >= NEED_FULL);

  (void)hipFuncSetAttribute((const void*)g8p_kernel<0>,
                            hipFuncAttributeMaxDynamicSharedMemorySize, 131072);
  (void)hipFuncSetAttribute((const void*)g8p_kernel<1>,
                            hipFuncAttributeMaxDynamicSharedMemorySize, 131072);
  (void)hipFuncSetAttribute((const void*)g8p_kernel<2>,
                            hipFuncAttributeMaxDynamicSharedMemorySize, 131072);
  (void)hipFuncSetAttribute((const void*)g8p_kernel<3>,
                            hipFuncAttributeMaxDynamicSharedMemorySize, 131072);

  hipMemsetAsync(ws + OFF_META, 0, 256, stream);

  if (full) {
    // regions: wgu@WGU_NEW (dead after merged1 -> eout), wdn@WDN_NEW
    unsigned short* wgu_bf = (unsigned short*)(ws + WGU_NEW);
    unsigned short* wdn_bf = (unsigned short*)(ws + WDN_NEW);
    unsigned short* eout   = (unsigned short*)(ws + WGU_NEW);

    cvt5_kernel<<<(CV_ALL + 255) / 256, 256, 0, stream>>>(
        WSG, WSU, WSD, WGU, WDN, wsg, wsu, wsd, wgu_bf, wdn_bf);
    logits_kernel<<<N_TOK / 4, 256, 0, stream>>>(X, GW, SEGW, lg, xbf);
    route_kernel<<<N_TOK / 256, 256, 0, stream>>>(lg, cnt, pps, ids, slotAB, twAB, sig);
    offs_aux_kernel<<<1, 64, 0, stream>>>(cnt, off, pps, Out + (size_t)N_TOK * HDIM);

    // merged sg1+eg1 (1024 flat blocks, XCD-swizzled)
    g8p_kernel<3><<<dim3(1024), 512, 131072, stream>>>(
        xbf, wsg, wsu, wgu_bf, nullptr, ids, cnt, off, sh, hexp, nullptr);
    // eg2 -> eout (overwrites dead wgu region)
    g8p_kernel<2><<<dim3(HDIM / 256, 8, NEXP), 512, 131072, stream>>>(
        hexp, nullptr, nullptr, nullptr, wdn_bf, ids, cnt, off, nullptr, nullptr, eout);
    // sg2 + fused combine -> final Out
    sg2c_kernel<1><<<dim3(HDIM / 128, N_TOK / 128), 256, 0, stream>>>(
        sh, wsd, sig, eout, slotAB, twAB, off, Out);
  } else {
    // fallback: sequential with aliased regions
    unsigned short* wgu_bf = (unsigned short*)(ws + OFF_SH);   // after sg2
    unsigned short* wdn_bf = (unsigned short*)(ws + OFF_XBF);  // after eg1
    unsigned short* eout   = (unsigned short*)(ws + OFF_SH);   // after eg1

    int n4 = (ISH * HDIM) / 4;
    cvt_kernel<<<(n4 + 255) / 256, 256, 0, stream>>>(WSG, wsg, n4);
    cvt_kernel<<<(n4 + 255) / 256, 256, 0, stream>>>(WSU, wsu, n4);
    n4 = (HDIM * ISH) / 4;
    cvt_kernel<<<(n4 + 255) / 256, 256, 0, stream>>>(WSD, wsd, n4);

    logits_kernel<<<N_TOK / 4, 256, 0, stream>>>(X, GW, SEGW, lg, xbf);
    route_kernel<<<N_TOK / 256, 256, 0, stream>>>(lg, cnt, pps, ids, slotAB, twAB, sig);
    offs_aux_kernel<<<1, 64, 0, stream>>>(cnt, off, pps, Out + (size_t)N_TOK * HDIM);

    g8p_kernel<0><<<dim3(16, 32), 512, 131072, stream>>>(
        xbf, wsg, wsu, nullptr, nullptr, ids, cnt, off, sh, nullptr, nullptr);
    sg2c_kernel<0><<<dim3(HDIM / 128, N_TOK / 128), 256, 0, stream>>>(
        sh, wsd, sig, nullptr, slotAB, twAB, off, Out);
    n4 = (NEXP * 2 * IEXP * HDIM) / 4;  // sh dead after sg2
    cvt_kernel<<<(n4 + 255) / 256, 256, 0, stream>>>(WGU, wgu_bf, n4);
    g8p_kernel<1><<<dim3(4, 8, NEXP), 512, 131072, stream>>>(
        xbf, nullptr, nullptr, wgu_bf, nullptr, ids, cnt, off, nullptr, hexp, nullptr);
    n4 = (NEXP * HDIM * IEXP) / 4;      // xbf dead after eg1
    cvt_kernel<<<(n4 + 255) / 256, 256, 0, stream>>>(WDN, wdn_bf, n4);
    g8p_kernel<2><<<dim3(HDIM / 256, 8, NEXP), 512, 131072, stream>>>(
        hexp, nullptr, nullptr, nullptr, wdn_bf, ids, cnt, off, nullptr, nullptr, eout);
    combine_kernel<<<N_TOK, 256, 0, stream>>>(eout, slotAB, twAB, off, Out);
  }
}

// Round 6
// 477.990 us; speedup vs baseline: 1.0600x; 1.0600x over previous
//
#include <hip/hip_runtime.h>
#include <hip/hip_bf16.h>
#include <stdint.h>

// MoE: N=8192 tokens, H=1024, E=16 experts (top-2), I=512, shared IS=2048.
// R10: revert R9's merged-kernel changes (XCD expert-chunk swizzle caused
//      eg1 straggler imbalance; B-in-regs ~neutral). g8p = R8-exact strict
//      loop + kt-unroll-2 (compile-time buffer parity -> address folding,
//      targets 25% VALUBusy). Keep R9's sg2c both-sides LDS swizzle.

#define N_TOK 8192
#define HDIM 1024
#define NEXP 16
#define IEXP 512
#define ISH 2048

typedef __bf16 bf16x8 __attribute__((ext_vector_type(8)));
typedef float f32x4 __attribute__((ext_vector_type(4)));

// ---- ws layout (bytes) ----
#define OFF_XBF   ((size_t)0)            // 16,777,216
#define OFF_WSG   ((size_t)16777216)     // 4,194,304
#define OFF_WSU   ((size_t)20971520)
#define OFF_WSD   ((size_t)25165824)
#define OFF_SH    ((size_t)29360128)     // 33,554,432 (sh; live until sg2c)
#define OFF_HEXP  ((size_t)62914560)     // 16,777,216
#define OFF_IDS   ((size_t)79691776)     // 16*8192*4 = 524,288
#define OFF_META  ((size_t)80216064)     // 256 B: cnt[16]@0, off[17]@64, pps[16]@144
#define OFF_SIG   ((size_t)80216320)     // 8192*4
#define OFF_LG    ((size_t)80249088)     // 8192*32*4 = 1,048,576
#define OFF_SLOT  ((size_t)81297664)     // 2*8192*4
#define OFF_TWAB  ((size_t)81363200)     // 2*8192*4  (end = 81,428,736)

#define WGU_NEW   ((size_t)81428736)                 // 33,554,432 (wgu -> eout)
#define WDN_NEW   ((size_t)(WGU_NEW + 33554432))     // 16,777,216
#define NEED_FULL ((size_t)(WDN_NEW + 16777216))     // 131,760,384

static __device__ __forceinline__ unsigned short f2bf(float f) {
  unsigned int u = __float_as_uint(f);
  u += 0x7fffu + ((u >> 16) & 1u);
  return (unsigned short)(u >> 16);
}
static __device__ __forceinline__ int pack_bf2(float a, float b) {
  return (int)f2bf(a) | ((int)f2bf(b) << 16);
}
static __device__ __forceinline__ float bf2f(unsigned short u) {
  return __uint_as_float(((unsigned int)u) << 16);
}
// async 16B global->LDS (LDS dest is wave-uniform base + lane*16)
static __device__ __forceinline__ void gl_lds16(const void* g, void* l) {
  __builtin_amdgcn_global_load_lds(
      (const __attribute__((address_space(1))) unsigned int*)g,
      (__attribute__((address_space(3))) unsigned int*)l, 16, 0, 0);
}

__global__ void cvt_kernel(const float* __restrict__ src,
                           unsigned short* __restrict__ dst, int n4) {
  int i = blockIdx.x * 256 + threadIdx.x;
  if (i >= n4) return;
  float4 v = ((const float4*)src)[i];
  uint2 o;
  o.x = (unsigned)pack_bf2(v.x, v.y);
  o.y = (unsigned)pack_bf2(v.z, v.w);
  ((uint2*)dst)[i] = o;
}

// all 5 weight converts in one dispatch (full path)
#define CV_WSG 524288
#define CV_WSU 1048576
#define CV_WSD 1572864
#define CV_WGU 5767168
#define CV_ALL 7864320
__global__ void cvt5_kernel(const float* __restrict__ WSG, const float* __restrict__ WSU,
                            const float* __restrict__ WSD, const float* __restrict__ WGU,
                            const float* __restrict__ WDN,
                            unsigned short* __restrict__ wsg, unsigned short* __restrict__ wsu,
                            unsigned short* __restrict__ wsd, unsigned short* __restrict__ wgu,
                            unsigned short* __restrict__ wdn) {
  int i = blockIdx.x * 256 + threadIdx.x;
  if (i >= CV_ALL) return;
  const float* src; unsigned short* dst; int k;
  if (i < CV_WSG)      { src = WSG; dst = wsg; k = i; }
  else if (i < CV_WSU) { src = WSU; dst = wsu; k = i - CV_WSG; }
  else if (i < CV_WSD) { src = WSD; dst = wsd; k = i - CV_WSU; }
  else if (i < CV_WGU) { src = WGU; dst = wgu; k = i - CV_WSD; }
  else                 { src = WDN; dst = wdn; k = i - CV_WGU; }
  float4 v = ((const float4*)src)[k];
  uint2 o;
  o.x = (unsigned)pack_bf2(v.x, v.y);
  o.y = (unsigned)pack_bf2(v.z, v.w);
  ((uint2*)dst)[k] = o;
}

// ---- phase 1: logits (wave/token) + fused X->bf16 convert
__global__ __launch_bounds__(256) void logits_kernel(
    const float* __restrict__ X, const float* __restrict__ GW,
    const float* __restrict__ SEGW, float* __restrict__ LG,
    unsigned short* __restrict__ XBF) {
  int wid = threadIdx.x >> 6, lane = threadIdx.x & 63;
  int tok = blockIdx.x * 4 + wid;
  const float* xr = X + (size_t)tok * HDIM;
  unsigned short* xw = XBF + (size_t)tok * HDIM;
  float xv[16];
#pragma unroll
  for (int i = 0; i < 16; i++) xv[i] = xr[lane + 64 * i];
#pragma unroll
  for (int i = 0; i < 16; i++) xw[lane + 64 * i] = f2bf(xv[i]);
  float myv = 0.f;
#pragma unroll
  for (int e = 0; e < 17; e++) {
    const float* wr = (e < 16) ? (GW + (size_t)e * HDIM) : SEGW;
    float p = 0.f;
#pragma unroll
    for (int i = 0; i < 16; i++) p += xv[i] * wr[lane + 64 * i];
#pragma unroll
    for (int off = 32; off >= 1; off >>= 1) p += __shfl_xor(p, off, 64);
    if (lane == e) myv = p;
  }
  if (lane < 17) LG[(size_t)tok * 32 + lane] = myv;
}

// ---- phase 2: softmax/top2/scatter
__global__ __launch_bounds__(256) void route_kernel(
    const float* __restrict__ LG, int* __restrict__ cnt,
    float* __restrict__ pps, int* __restrict__ ids,
    int* __restrict__ slotAB, float* __restrict__ twAB,
    float* __restrict__ sig) {
  __shared__ int lcnt[16];
  __shared__ int lbase[16];
  __shared__ float lps[16];
  int tid = threadIdx.x;
  int tok = blockIdx.x * 256 + tid;
  if (tid < 16) { lcnt[tid] = 0; lps[tid] = 0.f; }
  __syncthreads();
  const float4* row = (const float4*)(LG + (size_t)tok * 32);
  float4 v0 = row[0], v1 = row[1], v2 = row[2], v3 = row[3];
  float g16 = row[4].x;
  float lg[16] = {v0.x, v0.y, v0.z, v0.w, v1.x, v1.y, v1.z, v1.w,
                  v2.x, v2.y, v2.z, v2.w, v3.x, v3.y, v3.z, v3.w};
  float mx = lg[0];
#pragma unroll
  for (int e = 1; e < 16; e++) mx = fmaxf(mx, lg[e]);
  float pr[16], s = 0.f;
#pragma unroll
  for (int e = 0; e < 16; e++) { pr[e] = __expf(lg[e] - mx); s += pr[e]; }
  float inv_s = 1.f / s;
  float p1 = -1.f, p2 = -1.f; int i1 = 0, i2 = 0;
#pragma unroll
  for (int e = 0; e < 16; e++) {
    if (pr[e] > p1) { p2 = p1; i2 = i1; p1 = pr[e]; i1 = e; }
    else if (pr[e] > p2) { p2 = pr[e]; i2 = e; }
  }
  float wsum = p1 + p2;
  int s1 = atomicAdd(&lcnt[i1], 1);
  int s2 = atomicAdd(&lcnt[i2], 1);
#pragma unroll
  for (int e = 0; e < 16; e++) atomicAdd(&lps[e], pr[e] * inv_s);
  sig[tok] = 1.f / (1.f + __expf(-g16));
  __syncthreads();
  if (tid < 16) {
    lbase[tid] = atomicAdd(&cnt[tid], lcnt[tid]);
    atomicAdd(&pps[tid], lps[tid]);
  }
  __syncthreads();
  int sl1 = lbase[i1] + s1, sl2 = lbase[i2] + s2;
  ids[i1 * N_TOK + sl1] = tok;
  ids[i2 * N_TOK + sl2] = tok;
  slotAB[tok * 2]     = (i1 << 14) | sl1;
  slotAB[tok * 2 + 1] = (i2 << 14) | sl2;
  twAB[tok * 2]     = p1 / wsum;
  twAB[tok * 2 + 1] = p2 / wsum;
}

__global__ void offs_aux_kernel(const int* __restrict__ cnt, int* __restrict__ off,
                                const float* __restrict__ probs_sum,
                                float* __restrict__ out_aux) {
  if (threadIdx.x == 0 && blockIdx.x == 0) {
    int run = 0; float aux = 0.f;
    for (int e = 0; e < NEXP; e++) {
      off[e] = run; run += cnt[e];
      aux += ((float)cnt[e] / (float)(N_TOK * 2)) * (probs_sum[e] / (float)N_TOK);
    }
    off[16] = run;
    *out_aux = (float)NEXP * aux;
  }
}

// ======================================================================
// 256x256 BK=64 8-phase GEMM core, STRICT schedule (R8-exact) + unroll 2:
// per phase {ds_read frags; STG next slot; s_barrier; lgkmcnt(0);
// setprio(1); 16 MFMA; setprio(0); s_barrier}; vmcnt(4) once per K-tile
// (2 half-tiles in flight). kt loop unrolled x2 so buffer parity c/nb is
// compile-time -> LDS addresses fold to base+imm (VALU reduction).
// Swizzle: source 16B-block cb = blk^(row&7), LDS dest linear, ds_read
// same involution -> 0 bank conflicts (verified R5-R9).
// TMODE 0: sg1  A=xbf dense,    B=wsg/wsu 16-row interleave, silu -> sh
// TMODE 1: eg1  A=xbf gathered, B=wgu     16-row interleave, silu -> hexp
// TMODE 2: eg2  A=hexp,         B=wdn,    raw bf16 -> Eout
// TMODE 3: merged sg1+eg1 (flat 1024-block grid: id<512 sg1, else eg1)
// ======================================================================
template <int TMODE>
__global__ __launch_bounds__(512, 2) void g8p_kernel(
    const unsigned short* __restrict__ A0,
    const unsigned short* __restrict__ Bg,
    const unsigned short* __restrict__ Bu,
    const unsigned short* __restrict__ Bgu,
    const unsigned short* __restrict__ Bd,
    const int* __restrict__ ids, const int* __restrict__ cnt,
    const int* __restrict__ off,
    unsigned short* __restrict__ Osh,
    unsigned short* __restrict__ Ohex,
    unsigned short* __restrict__ Oeout) {
  constexpr int KD = (TMODE == 2) ? IEXP : HDIM;
  constexpr int NK = KD / 64;
  extern __shared__ unsigned short lds[];

  int rmode, e = 0, bx, by, m0step;
  if constexpr (TMODE == 3) {
    int id = blockIdx.x;
    if (id < 512) { rmode = 0; bx = id & 15; by = id >> 4; m0step = 8192; }
    else {
      int id2 = id - 512;
      rmode = 1; e = id2 >> 5; bx = id2 & 3; by = (id2 >> 2) & 7; m0step = 2048;
    }
  } else if constexpr (TMODE == 0) {
    rmode = 0; bx = blockIdx.x; by = blockIdx.y; m0step = 8192;
  } else if constexpr (TMODE == 1) {
    rmode = 1; e = blockIdx.z; bx = blockIdx.x; by = blockIdx.y;
    m0step = (int)gridDim.y * 256;
  } else {
    rmode = 2; e = blockIdx.z; bx = blockIdx.x; by = blockIdx.y;
    m0step = (int)gridDim.y * 256;
  }

  int ne, base = 0;
  if (rmode == 0) { ne = N_TOK; }
  else { ne = cnt[e]; base = off[e]; }

  const int t = threadIdx.x, lane = t & 63, w = t >> 6;
  const int fr = lane & 15, hi = lane >> 4;
  const int rq = hi * 4;
  const int Rm = (w >> 2) * 64;   // wave M base within a 128-row half
  const int wn = (w & 3) * 32;    // wave B-row base within a 128-row half
  const int srow = t >> 3;        // staging row-in-load
  const int sblk = t & 7;
  const int cb = (sblk ^ (srow & 7)) * 8;  // swizzled source k-elem offset
  const int s0 = ((0 + hi) ^ (fr & 7)) * 8;
  const int s1 = ((4 + hi) ^ (fr & 7)) * 8;
  const f32x4 z4 = {0.f, 0.f, 0.f, 0.f};

#define STG_A(buf, h, kt)                                                     \
  do {                                                                        \
    gl_lds16(apt[h][0] + (kt) * 64, &lds[(buf)*32768 + (h)*8192 + t * 8]);    \
    gl_lds16(apt[h][1] + (kt) * 64,                                           \
             &lds[(buf)*32768 + (h)*8192 + 4096 + t * 8]);                    \
  } while (0)
#define STG_B(buf, h, kt)                                                     \
  do {                                                                        \
    gl_lds16(bpt[h][0] + (kt) * 64,                                           \
             &lds[(buf)*32768 + 16384 + (h)*8192 + t * 8]);                   \
    gl_lds16(bpt[h][1] + (kt) * 64,                                           \
             &lds[(buf)*32768 + 16384 + (h)*8192 + 4096 + t * 8]);            \
  } while (0)

  for (int m0 = by * 256; m0 < ne; m0 += m0step) {
    // ---- per-thread staging source pointers (row fixed across K) ----
    const unsigned short* apt[2][2];
    const unsigned short* bpt[2][2];
#pragma unroll
    for (int h = 0; h < 2; h++)
#pragma unroll
      for (int l = 0; l < 2; l++) {
        int r = h * 128 + l * 64 + srow;
        // A row
        if (rmode == 0) {
          apt[h][l] = A0 + (size_t)(m0 + r) * HDIM + cb;
        } else if (rmode == 1) {
          int slot = m0 + r;
          int arow = (slot < ne) ? ids[e * N_TOK + slot] : 0;
          apt[h][l] = A0 + (size_t)arow * HDIM + cb;
        } else {
          int ra = base + m0 + r;
          if (ra > 16383) ra = 16383;
          apt[h][l] = A0 + (size_t)ra * IEXP + cb;
        }
        // B row
        if (rmode == 0) {
          int gcol = bx * 128 + ((r >> 5) << 4) + (r & 15);
          const unsigned short* W = (r & 16) ? Bu : Bg;
          bpt[h][l] = W + (size_t)gcol * HDIM + cb;
        } else if (rmode == 1) {
          int wrow = ((r & 16) ? 512 : 0) + bx * 128 + ((r >> 5) << 4) + (r & 15);
          bpt[h][l] = Bgu + ((size_t)e * 1024 + wrow) * HDIM + cb;
        } else {
          int nrow = bx * 256 + r;
          bpt[h][l] = Bd + ((size_t)e * HDIM + nrow) * IEXP + cb;
        }
      }

    f32x4 acc[8][4];
#pragma unroll
    for (int i = 0; i < 8; i++)
#pragma unroll
      for (int j = 0; j < 4; j++) acc[i][j] = z4;

    // ---- prologue: tile0 all 4 halves + tile1 {A-lo, B-hi} ----
    STG_A(0, 0, 0); STG_B(0, 1, 0); STG_A(0, 1, 0); STG_B(0, 0, 0);
    STG_A(1, 0, 1); STG_B(1, 1, 1);
    asm volatile("s_waitcnt vmcnt(4)" ::: "memory");
    __builtin_amdgcn_s_barrier();

#pragma unroll 2
    for (int kt = 0; kt < NK; ++kt) {
      const int c = kt & 1, nb = c ^ 1;
      const unsigned short* Ab = &lds[c * 32768];
      const unsigned short* Bb = &lds[c * 32768 + 16384];
      bf16x8 a[4][2], b[2][2];

      // ---- phase 0: (A-lo, B-lo) ----
#pragma unroll
      for (int i = 0; i < 4; i++) {
        int ro = (Rm + i * 16 + fr) * 64;
        a[i][0] = *(const bf16x8*)&Ab[ro + s0];
        a[i][1] = *(const bf16x8*)&Ab[ro + s1];
      }
#pragma unroll
      for (int j = 0; j < 2; j++) {
        int ro = (wn + j * 16 + fr) * 64;
        b[j][0] = *(const bf16x8*)&Bb[ro + s0];
        b[j][1] = *(const bf16x8*)&Bb[ro + s1];
      }
      if (kt + 1 < NK) STG_A(nb, 1, kt + 1);
      __builtin_amdgcn_s_barrier();
      asm volatile("s_waitcnt lgkmcnt(0)" ::: "memory");
      __builtin_amdgcn_s_setprio(1);
#pragma unroll
      for (int i = 0; i < 4; i++)
#pragma unroll
        for (int j = 0; j < 2; j++) {
          acc[i][j] = __builtin_amdgcn_mfma_f32_16x16x32_bf16(a[i][0], b[j][0], acc[i][j], 0, 0, 0);
          acc[i][j] = __builtin_amdgcn_mfma_f32_16x16x32_bf16(a[i][1], b[j][1], acc[i][j], 0, 0, 0);
        }
      __builtin_amdgcn_s_setprio(0);
      __builtin_amdgcn_s_barrier();

      // ---- phase 1: (A-lo, B-hi) ----
#pragma unroll
      for (int j = 0; j < 2; j++) {
        int ro = (128 + wn + j * 16 + fr) * 64;
        b[j][0] = *(const bf16x8*)&Bb[ro + s0];
        b[j][1] = *(const bf16x8*)&Bb[ro + s1];
      }
      if (kt + 1 < NK) STG_B(nb, 0, kt + 1);
      __builtin_amdgcn_s_barrier();
      asm volatile("s_waitcnt lgkmcnt(0)" ::: "memory");
      __builtin_amdgcn_s_setprio(1);
#pragma unroll
      for (int i = 0; i < 4; i++)
#pragma unroll
        for (int j = 0; j < 2; j++) {
          acc[i][2 + j] = __builtin_amdgcn_mfma_f32_16x16x32_bf16(a[i][0], b[j][0], acc[i][2 + j], 0, 0, 0);
          acc[i][2 + j] = __builtin_amdgcn_mfma_f32_16x16x32_bf16(a[i][1], b[j][1], acc[i][2 + j], 0, 0, 0);
        }
      __builtin_amdgcn_s_setprio(0);
      __builtin_amdgcn_s_barrier();

      // ---- phase 2: (A-hi, B-hi) ----
#pragma unroll
      for (int i = 0; i < 4; i++) {
        int ro = (128 + Rm + i * 16 + fr) * 64;
        a[i][0] = *(const bf16x8*)&Ab[ro + s0];
        a[i][1] = *(const bf16x8*)&Ab[ro + s1];
      }
      if (kt + 2 < NK) STG_A(c, 0, kt + 2);
      __builtin_amdgcn_s_barrier();
      asm volatile("s_waitcnt lgkmcnt(0)" ::: "memory");
      __builtin_amdgcn_s_setprio(1);
#pragma unroll
      for (int i = 0; i < 4; i++)
#pragma unroll
        for (int j = 0; j < 2; j++) {
          acc[4 + i][2 + j] = __builtin_amdgcn_mfma_f32_16x16x32_bf16(a[i][0], b[j][0], acc[4 + i][2 + j], 0, 0, 0);
          acc[4 + i][2 + j] = __builtin_amdgcn_mfma_f32_16x16x32_bf16(a[i][1], b[j][1], acc[4 + i][2 + j], 0, 0, 0);
        }
      __builtin_amdgcn_s_setprio(0);
      __builtin_amdgcn_s_barrier();

      // ---- phase 3: (A-hi, B-lo) ----
#pragma unroll
      for (int j = 0; j < 2; j++) {
        int ro = (wn + j * 16 + fr) * 64;
        b[j][0] = *(const bf16x8*)&Bb[ro + s0];
        b[j][1] = *(const bf16x8*)&Bb[ro + s1];
      }
      if (kt + 2 < NK) STG_B(c, 1, kt + 2);
      __builtin_amdgcn_s_barrier();
      asm volatile("s_waitcnt lgkmcnt(0)" ::: "memory");
      __builtin_amdgcn_s_setprio(1);
#pragma unroll
      for (int i = 0; i < 4; i++)
#pragma unroll
        for (int j = 0; j < 2; j++) {
          acc[4 + i][j] = __builtin_amdgcn_mfma_f32_16x16x32_bf16(a[i][0], b[j][0], acc[4 + i][j], 0, 0, 0);
          acc[4 + i][j] = __builtin_amdgcn_mfma_f32_16x16x32_bf16(a[i][1], b[j][1], acc[4 + i][j], 0, 0, 0);
        }
      __builtin_amdgcn_s_setprio(0);
      if (kt + 2 < NK) asm volatile("s_waitcnt vmcnt(4)" ::: "memory");
      else             asm volatile("s_waitcnt vmcnt(0)" ::: "memory");
      __builtin_amdgcn_s_barrier();
    }

    // ---- epilogue ----
#pragma unroll
    for (int i = 0; i < 8; i++) {
      int mloc = (i >> 2) * 128 + Rm + (i & 3) * 16 + rq;
      if (rmode == 2) {
#pragma unroll
        for (int j = 0; j < 4; j++) {
          int nn = bx * 256 + (j >> 1) * 128 + wn + (j & 1) * 16 + fr;
#pragma unroll
          for (int r = 0; r < 4; r++) {
            int slot = m0 + mloc + r;
            if (slot < ne)
              Oeout[(size_t)(base + slot) * HDIM + nn] = f2bf(acc[i][j][r]);
          }
        }
      } else {
        // silu(g)*u, bf16 store
#pragma unroll
        for (int p = 0; p < 2; p++) {
          int cc = bx * 128 + p * 64 + (w & 3) * 16 + fr;
#pragma unroll
          for (int r = 0; r < 4; r++) {
            int slot = m0 + mloc + r;
            float g = acc[i][2 * p][r], u = acc[i][2 * p + 1][r];
            float hv = g / (1.f + __expf(-g)) * u;
            if (rmode == 0) {
              Osh[(size_t)slot * ISH + cc] = f2bf(hv);
            } else if (slot < ne) {
              Ohex[(size_t)(base + slot) * IEXP + cc] = f2bf(hv);
            }
          }
        }
      }
    }
  }
#undef STG_A
#undef STG_B
}

// ---- sg2 (+ optional fused combine): Out = (H@Wd^T)*sig [+ twA*eoutA + twB*eoutB]
// 128x128 tile, 256 threads. Both-sides XOR swizzle (blk ^= row&3) on the
// 4x16B row blocks: fragment-read conflict 8-way -> 4-way (R9, verified).
template <int FUSE>
__global__ __launch_bounds__(256) void sg2c_kernel(
    const unsigned short* __restrict__ H, const unsigned short* __restrict__ Wd,
    const float* __restrict__ sig, const unsigned short* __restrict__ Eout,
    const int* __restrict__ slotAB, const float* __restrict__ twAB,
    const int* __restrict__ off, float* __restrict__ Out) {
  __shared__ __align__(16) unsigned short As[128 * 32];
  __shared__ __align__(16) unsigned short Bs[128 * 32];
  int m0 = blockIdx.y * 128, n0 = blockIdx.x * 128;
  int t = threadIdx.x, lane = t & 63, w = t >> 6;
  int wm = (w & 1) * 64, wn = (w >> 1) * 64;
  int arow = t >> 2;
  int akb = ((t & 3) ^ (arow & 3)) * 8;  // swizzled source column-block
  const unsigned short* apA0 = H + (size_t)(m0 + arow) * ISH + akb;
  const unsigned short* apA1 = H + (size_t)(m0 + 64 + arow) * ISH + akb;
  const unsigned short* apB0 = Wd + (size_t)(n0 + arow) * ISH + akb;
  const unsigned short* apB1 = Wd + (size_t)(n0 + 64 + arow) * ISH + akb;
  f32x4 z = {0.f, 0.f, 0.f, 0.f};
  f32x4 acc[4][4];
#pragma unroll
  for (int i = 0; i < 4; i++)
#pragma unroll
    for (int j = 0; j < 4; j++) acc[i][j] = z;
  int fr = lane & 15;
  int fcs = (((lane >> 4) ^ (fr & 3))) * 8;  // swizzled read block
  for (int k0 = 0; k0 < ISH; k0 += 32) {
    __syncthreads();
    gl_lds16(apA0 + k0, &As[t * 8]);
    gl_lds16(apA1 + k0, &As[2048 + t * 8]);
    gl_lds16(apB0 + k0, &Bs[t * 8]);
    gl_lds16(apB1 + k0, &Bs[2048 + t * 8]);
    __syncthreads();
    bf16x8 af[4], bfr[4];
#pragma unroll
    for (int i = 0; i < 4; i++) {
      af[i] = *(const bf16x8*)&As[(wm + i * 16 + fr) * 32 + fcs];
      bfr[i] = *(const bf16x8*)&Bs[(wn + i * 16 + fr) * 32 + fcs];
    }
#pragma unroll
    for (int i = 0; i < 4; i++)
#pragma unroll
      for (int j = 0; j < 4; j++)
        acc[i][j] = __builtin_amdgcn_mfma_f32_16x16x32_bf16(af[i], bfr[j], acc[i][j], 0, 0, 0);
  }
  int col = lane & 15, rq = (lane >> 4) * 4;
#pragma unroll
  for (int i = 0; i < 4; i++)
#pragma unroll
    for (int r = 0; r < 4; r++) {
      int mm = m0 + wm + i * 16 + rq + r;
      float sg = sig[mm];
      if (FUSE) {
        int sa = slotAB[mm * 2], sb = slotAB[mm * 2 + 1];
        float wa = twAB[mm * 2], wb = twAB[mm * 2 + 1];
        size_t ra = (size_t)(off[sa >> 14] + (sa & 16383)) * HDIM;
        size_t rb = (size_t)(off[sb >> 14] + (sb & 16383)) * HDIM;
#pragma unroll
        for (int j = 0; j < 4; j++) {
          int nn = n0 + wn + j * 16 + col;
          float ea = bf2f(Eout[ra + nn]);
          float eb = bf2f(Eout[rb + nn]);
          Out[(size_t)mm * HDIM + nn] = acc[i][j][r] * sg + wa * ea + wb * eb;
        }
      } else {
#pragma unroll
        for (int j = 0; j < 4; j++) {
          int nn = n0 + wn + j * 16 + col;
          Out[(size_t)mm * HDIM + nn] = acc[i][j][r] * sg;
        }
      }
    }
}

// ---- combine (fallback path only): Out[tok] += twA*eout[rowA] + twB*eout[rowB]
__global__ __launch_bounds__(256) void combine_kernel(
    const unsigned short* __restrict__ Eout, const int* __restrict__ slotAB,
    const float* __restrict__ twAB, const int* __restrict__ off,
    float* __restrict__ Out) {
  int tok = blockIdx.x, t = threadIdx.x;
  int sa = slotAB[tok * 2], sb = slotAB[tok * 2 + 1];
  float wa = twAB[tok * 2], wb = twAB[tok * 2 + 1];
  int ra = off[sa >> 14] + (sa & 16383);
  int rb = off[sb >> 14] + (sb & 16383);
  const ushort4 a4 = *(const ushort4*)(Eout + (size_t)ra * HDIM + t * 4);
  const ushort4 b4 = *(const ushort4*)(Eout + (size_t)rb * HDIM + t * 4);
  float* po = Out + (size_t)tok * HDIM + t * 4;
  float4 o = *(const float4*)po;
  o.x += wa * bf2f(a4.x) + wb * bf2f(b4.x);
  o.y += wa * bf2f(a4.y) + wb * bf2f(b4.y);
  o.z += wa * bf2f(a4.z) + wb * bf2f(b4.z);
  o.w += wa * bf2f(a4.w) + wb * bf2f(b4.w);
  *(float4*)po = o;
}

extern "C" void kernel_launch(void* const* d_in, const int* in_sizes, int n_in,
                              void* d_out, int out_size, void* d_ws, size_t ws_size,
                              hipStream_t stream) {
  const float* X   = (const float*)d_in[0];
  const float* GW  = (const float*)d_in[1];
  const float* WGU = (const float*)d_in[2];
  const float* WDN = (const float*)d_in[3];
  const float* WSG = (const float*)d_in[4];
  const float* WSU = (const float*)d_in[5];
  const float* WSD = (const float*)d_in[6];
  const float* SEGW = (const float*)d_in[7];
  float* Out = (float*)d_out;
  char* ws = (char*)d_ws;

  unsigned short* xbf  = (unsigned short*)(ws + OFF_XBF);
  unsigned short* wsg  = (unsigned short*)(ws + OFF_WSG);
  unsigned short* wsu  = (unsigned short*)(ws + OFF_WSU);
  unsigned short* wsd  = (unsigned short*)(ws + OFF_WSD);
  unsigned short* sh   = (unsigned short*)(ws + OFF_SH);
  unsigned short* hexp = (unsigned short*)(ws + OFF_HEXP);
  int*   ids  = (int*)(ws + OFF_IDS);
  int*   cnt  = (int*)(ws + OFF_META);
  int*   off  = (int*)(ws + OFF_META + 64);
  float* pps  = (float*)(ws + OFF_META + 144);
  float* sig  = (float*)(ws + OFF_SIG);
  float* lg   = (float*)(ws + OFF_LG);
  int*   slotAB = (int*)(ws + OFF_SLOT);
  float* twAB   = (float*)(ws + OFF_TWAB);

  const bool full = (ws_size >= NEED_FULL);

  (void)hipFuncSetAttribute((const void*)g8p_kernel<0>,
                            hipFuncAttributeMaxDynamicSharedMemorySize, 131072);
  (void)hipFuncSetAttribute((const void*)g8p_kernel<1>,
                            hipFuncAttributeMaxDynamicSharedMemorySize, 131072);
  (void)hipFuncSetAttribute((const void*)g8p_kernel<2>,
                            hipFuncAttributeMaxDynamicSharedMemorySize, 131072);
  (void)hipFuncSetAttribute((const void*)g8p_kernel<3>,
                            hipFuncAttributeMaxDynamicSharedMemorySize, 131072);

  hipMemsetAsync(ws + OFF_META, 0, 256, stream);

  if (full) {
    // regions: wgu@WGU_NEW (dead after merged1 -> eout), wdn@WDN_NEW
    unsigned short* wgu_bf = (unsigned short*)(ws + WGU_NEW);
    unsigned short* wdn_bf = (unsigned short*)(ws + WDN_NEW);
    unsigned short* eout   = (unsigned short*)(ws + WGU_NEW);

    cvt5_kernel<<<(CV_ALL + 255) / 256, 256, 0, stream>>>(
        WSG, WSU, WSD, WGU, WDN, wsg, wsu, wsd, wgu_bf, wdn_bf);
    logits_kernel<<<N_TOK / 4, 256, 0, stream>>>(X, GW, SEGW, lg, xbf);
    route_kernel<<<N_TOK / 256, 256, 0, stream>>>(lg, cnt, pps, ids, slotAB, twAB, sig);
    offs_aux_kernel<<<1, 64, 0, stream>>>(cnt, off, pps, Out + (size_t)N_TOK * HDIM);

    // merged sg1+eg1 (1024 flat blocks)
    g8p_kernel<3><<<dim3(1024), 512, 131072, stream>>>(
        xbf, wsg, wsu, wgu_bf, nullptr, ids, cnt, off, sh, hexp, nullptr);
    // eg2 -> eout (overwrites dead wgu region)
    g8p_kernel<2><<<dim3(HDIM / 256, 8, NEXP), 512, 131072, stream>>>(
        hexp, nullptr, nullptr, nullptr, wdn_bf, ids, cnt, off, nullptr, nullptr, eout);
    // sg2 + fused combine -> final Out
    sg2c_kernel<1><<<dim3(HDIM / 128, N_TOK / 128), 256, 0, stream>>>(
        sh, wsd, sig, eout, slotAB, twAB, off, Out);
  } else {
    // fallback: sequential with aliased regions
    unsigned short* wgu_bf = (unsigned short*)(ws + OFF_SH);   // after sg2
    unsigned short* wdn_bf = (unsigned short*)(ws + OFF_XBF);  // after eg1
    unsigned short* eout   = (unsigned short*)(ws + OFF_SH);   // after eg1

    int n4 = (ISH * HDIM) / 4;
    cvt_kernel<<<(n4 + 255) / 256, 256, 0, stream>>>(WSG, wsg, n4);
    cvt_kernel<<<(n4 + 255) / 256, 256, 0, stream>>>(WSU, wsu, n4);
    n4 = (HDIM * ISH) / 4;
    cvt_kernel<<<(n4 + 255) / 256, 256, 0, stream>>>(WSD, wsd, n4);

    logits_kernel<<<N_TOK / 4, 256, 0, stream>>>(X, GW, SEGW, lg, xbf);
    route_kernel<<<N_TOK / 256, 256, 0, stream>>>(lg, cnt, pps, ids, slotAB, twAB, sig);
    offs_aux_kernel<<<1, 64, 0, stream>>>(cnt, off, pps, Out + (size_t)N_TOK * HDIM);

    g8p_kernel<0><<<dim3(16, 32), 512, 131072, stream>>>(
        xbf, wsg, wsu, nullptr, nullptr, ids, cnt, off, sh, nullptr, nullptr);
    sg2c_kernel<0><<<dim3(HDIM / 128, N_TOK / 128), 256, 0, stream>>>(
        sh, wsd, sig, nullptr, slotAB, twAB, off, Out);
    n4 = (NEXP * 2 * IEXP * HDIM) / 4;  // sh dead after sg2
    cvt_kernel<<<(n4 + 255) / 256, 256, 0, stream>>>(WGU, wgu_bf, n4);
    g8p_kernel<1><<<dim3(4, 8, NEXP), 512, 131072, stream>>>(
        xbf, nullptr, nullptr, wgu_bf, nullptr, ids, cnt, off, nullptr, hexp, nullptr);
    n4 = (NEXP * HDIM * IEXP) / 4;      // xbf dead after eg1
    cvt_kernel<<<(n4 + 255) / 256, 256, 0, stream>>>(WDN, wdn_bf, n4);
    g8p_kernel<2><<<dim3(HDIM / 256, 8, NEXP), 512, 131072, stream>>>(
        hexp, nullptr, nullptr, nullptr, wdn_bf, ids, cnt, off, nullptr, nullptr, eout);
    combine_kernel<<<N_TOK, 256, 0, stream>>>(eout, slotAB, twAB, off, Out);
  }
}